// Round 13
// baseline (405.967 us; speedup 1.0000x reference)
//
#include <hip/hip_runtime.h>

#define N_NODES 100000
#define N_GRAPHS 64
#define N_EDGES 600000
#define BN_EPS 1e-5f

typedef unsigned short bf16_t;

__device__ __forceinline__ unsigned short f2bf(float f) {
    unsigned int u = __float_as_uint(f);
    u += 0x7FFF + ((u >> 16) & 1);
    return (unsigned short)(u >> 16);
}
__device__ __forceinline__ float4 bf2f4(uint2 p) {
    float4 r;
    r.x = __uint_as_float(p.x << 16);
    r.y = __uint_as_float(p.x & 0xFFFF0000u);
    r.z = __uint_as_float(p.y << 16);
    r.w = __uint_as_float(p.y & 0xFFFF0000u);
    return r;
}
__device__ __forceinline__ uint2 pack4(float a, float b, float c, float d) {
    uint2 p;
    p.x = (unsigned)f2bf(a) | ((unsigned)f2bf(b) << 16);
    p.y = (unsigned)f2bf(c) | ((unsigned)f2bf(d) << 16);
    return p;
}

// ===========================================================================
// CSR build: deg histogram -> scan -> cursor fill (+graph bounds merged).
// ===========================================================================
__global__ void deg_hist_kernel(const int* __restrict__ dst,
                                int* __restrict__ deg, int n_edges) {
    int e = blockIdx.x * blockDim.x + threadIdx.x;
    if (e < n_edges) atomicAdd(&deg[dst[e]], 1);
}

__global__ void scan1_kernel(const int* __restrict__ deg, int* __restrict__ excl,
                             int* __restrict__ partials, int n) {
    __shared__ int s[1024];
    int i = blockIdx.x * 1024 + threadIdx.x;
    int v = (i < n) ? deg[i] : 0;
    s[threadIdx.x] = v;
    __syncthreads();
    for (int off = 1; off < 1024; off <<= 1) {
        int t = (threadIdx.x >= (unsigned)off) ? s[threadIdx.x - off] : 0;
        __syncthreads();
        s[threadIdx.x] += t;
        __syncthreads();
    }
    if (i < n) excl[i] = s[threadIdx.x] - v;
    if (threadIdx.x == 1023) partials[blockIdx.x] = s[1023];
}

__global__ void scan2_kernel(int* partials, int nb) {
    __shared__ int s[128];
    int t = threadIdx.x;
    int v = (t < nb) ? partials[t] : 0;
    s[t] = v;
    __syncthreads();
    for (int off = 1; off < 128; off <<= 1) {
        int u = (t >= off) ? s[t - off] : 0;
        __syncthreads();
        s[t] += u;
        __syncthreads();
    }
    if (t < nb) partials[t] = s[t] - v;
}

__global__ void scan3_kernel(int* __restrict__ rowptr, const int* __restrict__ partials,
                             int n, int total) {
    int i = blockIdx.x * blockDim.x + threadIdx.x;
    if (i < n) rowptr[i] += partials[i >> 10];
    else if (i == n) rowptr[n] = total;
}

__global__ void fill_bounds_kernel(const int* __restrict__ src, const int* __restrict__ dst,
                                   const int* __restrict__ rowptr, int* __restrict__ cursor,
                                   int* __restrict__ eids, const int* __restrict__ batch,
                                   int* __restrict__ gstart, int n_edges, int n_nodes) {
    int e = blockIdx.x * blockDim.x + threadIdx.x;
    if (e < n_edges) {
        int t = dst[e];
        int pos = rowptr[t] + atomicAdd(&cursor[t], 1);
        eids[pos] = src[e];
    }
    if (e < n_nodes) {
        if (e == 0) {
            for (int g = 0; g <= batch[0]; ++g) gstart[g] = 0;
        } else {
            int b0 = batch[e - 1], b1 = batch[e];
            for (int g = b0 + 1; g <= b1; ++g) gstart[g] = e;
        }
        if (e == n_nodes - 1) {
            for (int g = batch[e] + 1; g <= N_GRAPHS; ++g) gstart[g] = n_nodes;
        }
    }
}

// ===========================================================================
// Prep, all 3 layers in one launch (blockIdx.y = layer); y==0 blocks also
// zero deg/cursor.
// ===========================================================================
struct LayerPrep {
    const float *w1, *w2, *b2, *g, *bb, *m, *v;
    float *w1T, *w2sT, *bias2;
    int DIN, DOUT;
};
struct PrepAll { LayerPrep l[3]; };

__global__ void prep_all_kernel(PrepAll pa, int* __restrict__ deg,
                                int* __restrict__ cursor) {
    LayerPrep P = pa.l[blockIdx.y];
    int i = blockIdx.x * blockDim.x + threadIdx.x;
    if (blockIdx.y == 0) {
        int stride = gridDim.x * blockDim.x;
        for (int k = i; k < N_NODES; k += stride) { deg[k] = 0; cursor[k] = 0; }
    }
    if (i < 64 * P.DIN) {
        int j = i / P.DIN, k = i % P.DIN;
        P.w1T[i] = P.w1[k * 64 + j];
    }
    int i2 = i - 64 * P.DIN;
    if (i2 >= 0 && i2 < P.DOUT * 64) {
        int c = i2 / 64, j = i2 % 64;
        float s = P.g[c] * rsqrtf(P.v[c] + BN_EPS);
        P.w2sT[i2] = P.w2[j * P.DOUT + c] * s;
    }
    int i3 = i2 - P.DOUT * 64;
    if (i3 >= 0 && i3 < P.DOUT) {
        float s = P.g[i3] * rsqrtf(P.v[i3] + BN_EPS);
        P.bias2[i3] = (P.b2[i3] - P.m[i3]) * s + P.bb[i3];
    }
}

// ===========================================================================
// pre-GEMM (R10-proven): y = x @ W1_0 (128 -> 64), bf16 out. 64-node tile,
// 256 threads, 4 rows/thread.
// ===========================================================================
__global__ __launch_bounds__(256)
void pre_gemm_kernel(const float* __restrict__ x, const float* __restrict__ w1T,
                     bf16_t* __restrict__ y, int n_nodes) {
    __shared__ float w1s[64 * 128];
    const int tid = threadIdx.x;
    const long base = (long)blockIdx.x * 64;

    const float4* gw1 = (const float4*)w1T;
    for (int i4 = tid; i4 < 16 * 128; i4 += 256) {
        int row = i4 >> 5, k4 = i4 & 31;
        *(float4*)&w1s[row * 128 + ((k4 ^ ((row >> 2) & 7)) << 2)] = gw1[i4];
    }
    __syncthreads();

    const int jg = tid & 15, ng = tid >> 4, xw = jg & 7;
    const float* wp = &w1s[(jg * 4) * 128];
    const float4* xv = (const float4*)x;
    long r[4];
    #pragma unroll
    for (int i = 0; i < 4; ++i) {
        long rr = base + ng * 4 + i;
        r[i] = (rr < n_nodes) ? rr : (n_nodes - 1);  // clamp: x has no padding
    }
    float acc[4][4] = {};
    #pragma unroll 4
    for (int k4 = 0; k4 < 32; ++k4) {
        const int ko = (k4 ^ xw) << 2;
        float4 w0 = *(const float4*)&wp[0 * 128 + ko];
        float4 w1v = *(const float4*)&wp[1 * 128 + ko];
        float4 w2v = *(const float4*)&wp[2 * 128 + ko];
        float4 w3v = *(const float4*)&wp[3 * 128 + ko];
        #pragma unroll
        for (int i = 0; i < 4; ++i) {
            float4 a = xv[r[i] * 32 + k4];
            acc[i][0] = fmaf(a.x, w0.x, fmaf(a.y, w0.y, fmaf(a.z, w0.z, fmaf(a.w, w0.w, acc[i][0]))));
            acc[i][1] = fmaf(a.x, w1v.x, fmaf(a.y, w1v.y, fmaf(a.z, w1v.z, fmaf(a.w, w1v.w, acc[i][1]))));
            acc[i][2] = fmaf(a.x, w2v.x, fmaf(a.y, w2v.y, fmaf(a.z, w2v.z, fmaf(a.w, w2v.w, acc[i][2]))));
            acc[i][3] = fmaf(a.x, w3v.x, fmaf(a.y, w3v.y, fmaf(a.z, w3v.z, fmaf(a.w, w3v.w, acc[i][3]))));
        }
    }
    #pragma unroll
    for (int i = 0; i < 4; ++i) {
        long n = base + ng * 4 + i;
        if (n < n_nodes) {
            *(uint2*)(y + n * 64 + jg * 4) = pack4(acc[i][0], acc[i][1], acc[i][2], acc[i][3]);
        }
    }
}

// ===========================================================================
// Device helper: gather a 64-node tile (bf16 y rows) into LDS sT as
// t = relu(aggr + b1), fp32. 16 lanes/node, 4 passes of 16 nodes.
// y is always the PREVIOUS layer's buffer (ping-pong; never this kernel's
// output) — R7's in-place race is structurally excluded.
// ===========================================================================
#define SS 68
__device__ __forceinline__ void gather_tile_lds(const bf16_t* __restrict__ y,
                                                const int* __restrict__ rowptr,
                                                const int* __restrict__ eids,
                                                const float* __restrict__ b1,
                                                float* sT, long base, int n_nodes,
                                                int tid) {
    const uint2* yv = (const uint2*)y;
    const int f4 = tid & 15;
    const int gidx = tid >> 4;
    const float4 bv = ((const float4*)b1)[f4];
    #pragma unroll
    for (int pass = 0; pass < 4; ++pass) {
        int nl = pass * 16 + gidx;
        long node = base + nl;
        float4 acc = {0.0f, 0.0f, 0.0f, 0.0f};
        if (node < n_nodes) {
            acc = bf2f4(yv[node * 16 + f4]);
            int b = rowptr[node], e = rowptr[node + 1];
            int i = b;
            for (; i + 3 < e; i += 4) {
                int s0 = eids[i], s1 = eids[i + 1], s2 = eids[i + 2], s3 = eids[i + 3];
                uint2 q0 = yv[(long)s0 * 16 + f4];
                uint2 q1 = yv[(long)s1 * 16 + f4];
                uint2 q2 = yv[(long)s2 * 16 + f4];
                uint2 q3 = yv[(long)s3 * 16 + f4];
                float4 r0 = bf2f4(q0), r1 = bf2f4(q1), r2 = bf2f4(q2), r3 = bf2f4(q3);
                acc.x += (r0.x + r1.x) + (r2.x + r3.x);
                acc.y += (r0.y + r1.y) + (r2.y + r3.y);
                acc.z += (r0.z + r1.z) + (r2.z + r3.z);
                acc.w += (r0.w + r1.w) + (r2.w + r3.w);
            }
            for (; i < e; ++i) {
                int s = eids[i];
                float4 r = bf2f4(yv[(long)s * 16 + f4]);
                acc.x += r.x; acc.y += r.y; acc.z += r.z; acc.w += r.w;
            }
        }
        float4 o;
        o.x = fmaxf(acc.x + bv.x, 0.0f);
        o.y = fmaxf(acc.y + bv.y, 0.0f);
        o.z = fmaxf(acc.z + bv.z, 0.0f);
        o.w = fmaxf(acc.w + bv.w, 0.0f);
        *(float4*)&sT[nl * SS + f4 * 4] = o;
    }
}

// ===========================================================================
// Fused mid layer (gather + MLP): sT <- gather(y); h = relu(t@W2s+bias2);
// sT <- h; ynext = h @ W1n (bf16). LDS 17.4+16 KB -> 4 blocks/CU; sibling
// blocks co-schedule gather (VMEM) under GEMM (VALU).
// ===========================================================================
__global__ __launch_bounds__(256)
void fused_mid_kernel(const bf16_t* __restrict__ y, const int* __restrict__ rowptr,
                      const int* __restrict__ eids, const float* __restrict__ b1,
                      const float* __restrict__ w2sT, const float* __restrict__ bias2,
                      const float* __restrict__ w1nT, bf16_t* __restrict__ ynext,
                      int n_nodes) {
    __shared__ float sT[64 * SS];
    __shared__ float wbuf[64 * 64];
    const int tid = threadIdx.x;
    const long base = (long)blockIdx.x * 64;

    const float4* gw2 = (const float4*)w2sT;
    for (int i4 = tid; i4 < 16 * 64; i4 += 256) {
        int row = i4 >> 4, k4 = i4 & 15;
        *(float4*)&wbuf[row * 64 + ((k4 ^ ((row >> 2) & 7)) << 2)] = gw2[i4];
    }
    gather_tile_lds(y, rowptr, eids, b1, sT, base, n_nodes, tid);
    __syncthreads();

    const int jg = tid & 15, ng = tid >> 4, xw = jg & 7;

    // phase 1: h = relu(t @ w2s + bias2), t read broadcast from sT
    float h[4][4];
    {
        const float* ap = &sT[(ng * 4) * SS];
        const float* wp = &wbuf[(jg * 4) * 64];
        float acc[4][4] = {};
        #pragma unroll 4
        for (int k4 = 0; k4 < 16; ++k4) {
            const int ko = (k4 ^ xw) << 2;
            float4 w0 = *(const float4*)&wp[0 * 64 + ko];
            float4 w1v = *(const float4*)&wp[1 * 64 + ko];
            float4 w2v = *(const float4*)&wp[2 * 64 + ko];
            float4 w3v = *(const float4*)&wp[3 * 64 + ko];
            #pragma unroll
            for (int i = 0; i < 4; ++i) {
                float4 a = *(const float4*)&ap[i * SS + k4 * 4];
                acc[i][0] = fmaf(a.x, w0.x, fmaf(a.y, w0.y, fmaf(a.z, w0.z, fmaf(a.w, w0.w, acc[i][0]))));
                acc[i][1] = fmaf(a.x, w1v.x, fmaf(a.y, w1v.y, fmaf(a.z, w1v.z, fmaf(a.w, w1v.w, acc[i][1]))));
                acc[i][2] = fmaf(a.x, w2v.x, fmaf(a.y, w2v.y, fmaf(a.z, w2v.z, fmaf(a.w, w2v.w, acc[i][2]))));
                acc[i][3] = fmaf(a.x, w3v.x, fmaf(a.y, w3v.y, fmaf(a.z, w3v.z, fmaf(a.w, w3v.w, acc[i][3]))));
            }
        }
        float4 bv = *(const float4*)&bias2[jg * 4];
        #pragma unroll
        for (int i = 0; i < 4; ++i) {
            h[i][0] = fmaxf(acc[i][0] + bv.x, 0.0f);
            h[i][1] = fmaxf(acc[i][1] + bv.y, 0.0f);
            h[i][2] = fmaxf(acc[i][2] + bv.z, 0.0f);
            h[i][3] = fmaxf(acc[i][3] + bv.w, 0.0f);
        }
    }
    __syncthreads();  // all phase-1 sT/wbuf reads done

    // overwrite sT with h; restage wbuf with w1n
    #pragma unroll
    for (int i = 0; i < 4; ++i) {
        float4 hv = {h[i][0], h[i][1], h[i][2], h[i][3]};
        *(float4*)&sT[(ng * 4 + i) * SS + jg * 4] = hv;
    }
    const float4* gw1n = (const float4*)w1nT;
    for (int i4 = tid; i4 < 16 * 64; i4 += 256) {
        int row = i4 >> 4, k4 = i4 & 15;
        *(float4*)&wbuf[row * 64 + ((k4 ^ ((row >> 2) & 7)) << 2)] = gw1n[i4];
    }
    __syncthreads();

    // phase 2: ynext = h @ w1n (bf16 out)
    {
        const float* ap = &sT[(ng * 4) * SS];
        const float* wp = &wbuf[(jg * 4) * 64];
        float acc[4][4] = {};
        #pragma unroll 4
        for (int k4 = 0; k4 < 16; ++k4) {
            const int ko = (k4 ^ xw) << 2;
            float4 w0 = *(const float4*)&wp[0 * 64 + ko];
            float4 w1v = *(const float4*)&wp[1 * 64 + ko];
            float4 w2v = *(const float4*)&wp[2 * 64 + ko];
            float4 w3v = *(const float4*)&wp[3 * 64 + ko];
            #pragma unroll
            for (int i = 0; i < 4; ++i) {
                float4 a = *(const float4*)&ap[i * SS + k4 * 4];
                acc[i][0] = fmaf(a.x, w0.x, fmaf(a.y, w0.y, fmaf(a.z, w0.z, fmaf(a.w, w0.w, acc[i][0]))));
                acc[i][1] = fmaf(a.x, w1v.x, fmaf(a.y, w1v.y, fmaf(a.z, w1v.z, fmaf(a.w, w1v.w, acc[i][1]))));
                acc[i][2] = fmaf(a.x, w2v.x, fmaf(a.y, w2v.y, fmaf(a.z, w2v.z, fmaf(a.w, w2v.w, acc[i][2]))));
                acc[i][3] = fmaf(a.x, w3v.x, fmaf(a.y, w3v.y, fmaf(a.z, w3v.z, fmaf(a.w, w3v.w, acc[i][3]))));
            }
        }
        #pragma unroll
        for (int i = 0; i < 4; ++i) {
            long n = base + ng * 4 + i;
            if (n < n_nodes) {
                *(uint2*)(ynext + n * 64 + jg * 4) = pack4(acc[i][0], acc[i][1], acc[i][2], acc[i][3]);
            }
        }
    }
}

// ===========================================================================
// Fused final layer (gather + MLP): sT <- gather(y); out = relu(t@W2s+bias2),
// 96-wide fp32. LDS 17.4+24.6 KB -> 3 blocks/CU.
// ===========================================================================
__global__ __launch_bounds__(256)
void fused_final_kernel(const bf16_t* __restrict__ y, const int* __restrict__ rowptr,
                        const int* __restrict__ eids, const float* __restrict__ b1,
                        const float* __restrict__ w2sT, const float* __restrict__ bias2,
                        float* __restrict__ out, int n_nodes) {
    constexpr int CPT = 6;
    __shared__ float sT[64 * SS];
    __shared__ float w2s[96 * 64];
    const int tid = threadIdx.x;
    const long base = (long)blockIdx.x * 64;

    const float4* gw2 = (const float4*)w2sT;
    for (int i4 = tid; i4 < 96 * 16; i4 += 256) {
        int row = i4 >> 4, k4 = i4 & 15;
        *(float4*)&w2s[row * 64 + ((k4 ^ ((row / CPT) & 7)) << 2)] = gw2[i4];
    }
    gather_tile_lds(y, rowptr, eids, b1, sT, base, n_nodes, tid);
    __syncthreads();

    const int cg_ = tid & 15, ng = tid >> 4, xw = cg_ & 7;
    const float* hp = &sT[(ng * 4) * SS];
    const float* wp = &w2s[(cg_ * CPT) * 64];
    float acc[4][CPT] = {};
    #pragma unroll 4
    for (int k4 = 0; k4 < 16; ++k4) {
        const int ko = (k4 ^ xw) << 2;
        float4 wv[CPT];
        #pragma unroll
        for (int c = 0; c < CPT; ++c) wv[c] = *(const float4*)&wp[c * 64 + ko];
        #pragma unroll
        for (int i = 0; i < 4; ++i) {
            float4 h = *(const float4*)&hp[i * SS + k4 * 4];
            #pragma unroll
            for (int c = 0; c < CPT; ++c)
                acc[i][c] = fmaf(h.x, wv[c].x, fmaf(h.y, wv[c].y, fmaf(h.z, wv[c].z, fmaf(h.w, wv[c].w, acc[i][c]))));
        }
    }
    float bv[CPT];
    #pragma unroll
    for (int c = 0; c < CPT; ++c) bv[c] = bias2[cg_ * CPT + c];
    #pragma unroll
    for (int i = 0; i < 4; ++i) {
        long n = base + ng * 4 + i;
        if (n < n_nodes) {
            float* op = out + n * 96 + cg_ * CPT;
            #pragma unroll
            for (int c = 0; c < CPT; ++c) op[c] = fmaxf(acc[i][c] + bv[c], 0.0f);
        }
    }
}

// ===========================================================================
// Mean-pool: per-(graph,segment) partials, non-atomic; finalize reduces.
// ===========================================================================
#define POOL_SPLIT 16
__global__ __launch_bounds__(192)
void pool_seg_kernel(const float* __restrict__ h, const int* __restrict__ gstart,
                     float* __restrict__ part) {
    int g = blockIdx.x >> 4;
    int s = blockIdx.x & 15;
    int lo = gstart[g], hi = gstart[g + 1];
    int len = hi - lo;
    int seg = (len + POOL_SPLIT - 1) / POOL_SPLIT;
    int a = lo + s * seg;
    int b = a + seg; if (b > hi) b = hi;

    int f4 = threadIdx.x % 24;
    int chain = threadIdx.x / 24;
    const float4* hv = (const float4*)h;
    float4 acc = {0.0f, 0.0f, 0.0f, 0.0f};
    for (int n = a + chain; n < b; n += 8) {
        float4 v = hv[(long)n * 24 + f4];
        acc.x += v.x; acc.y += v.y; acc.z += v.z; acc.w += v.w;
    }
    __shared__ float4 red[8][24];
    red[chain][f4] = acc;
    __syncthreads();
    if (threadIdx.x < 24) {
        float4 t = red[0][threadIdx.x];
        #pragma unroll
        for (int c = 1; c < 8; ++c) {
            float4 r = red[c][threadIdx.x];
            t.x += r.x; t.y += r.y; t.z += r.z; t.w += r.w;
        }
        *(float4*)&part[((long)blockIdx.x) * 96 + threadIdx.x * 4] = t;
    }
}

__global__ void finalize_kernel(const float* __restrict__ part,
                                const int* __restrict__ gstart,
                                float* __restrict__ out) {
    int i = blockIdx.x * blockDim.x + threadIdx.x;
    if (i >= N_GRAPHS * 96) return;
    int g = i / 96, c = i - g * 96;
    float s = 0.0f;
    #pragma unroll
    for (int k = 0; k < POOL_SPLIT; ++k) s += part[((long)g * POOL_SPLIT + k) * 96 + c];
    float cnt = (float)(gstart[g + 1] - gstart[g]);
    out[i] = s / fmaxf(cnt, 1.0f);
}

// ---------------------------------------------------------------------------
static inline int cdiv_l(long a, int b) { return (int)((a + b - 1) / b); }

extern "C" void kernel_launch(void* const* d_in, const int* in_sizes, int n_in,
                              void* d_out, int out_size, void* d_ws, size_t ws_size,
                              hipStream_t stream) {
    const float* x     = (const float*)d_in[0];
    const int*   ei    = (const int*)d_in[1];
    const int*   src   = ei;
    const int*   dst   = ei + N_EDGES;
    const int*   batch = (const int*)d_in[2];

    const float* P[3][8];
    int p = 3;
    for (int l = 0; l < 3; ++l)
        for (int q = 0; q < 8; ++q)
            P[l][q] = (const float*)d_in[p++];

    const long NP = N_NODES + 128;
    char* wsb   = (char*)d_ws;
    bf16_t* yA  = (bf16_t*)wsb;                       // NP*64 bf16 (ping)
    bf16_t* yB  = yA + NP * 64;                       // NP*64 bf16 (pong)
    float* h2   = (float*)(yB + NP * 64);             // NP*96 fp32
    float* q    = h2 + NP * 96;
    float* w1T[3], *w2sT[3], *bias2[3];
    for (int l = 0; l < 3; ++l) {
        w1T[l] = q;   q += 64 * 128;
        w2sT[l] = q;  q += 96 * 64;
        bias2[l] = q; q += 96;
    }
    float* part   = q;                                // 64*16*96
    int* gstart   = (int*)(part + N_GRAPHS * POOL_SPLIT * 96);
    int* deg      = gstart + 72;
    int* cursor   = deg + N_NODES;
    int* partials = cursor + N_NODES;
    int* rowptr   = partials + 128;
    int* eids     = rowptr + (N_NODES + 1);

    const int B = 256;
    const int DIN[3]  = {128, 64, 64};
    const int DOUT[3] = {64, 64, 96};

    // ---- prep (one launch; also zeroes deg/cursor) ----
    PrepAll pa;
    for (int l = 0; l < 3; ++l) {
        pa.l[l].w1 = P[l][0]; pa.l[l].w2 = P[l][2]; pa.l[l].b2 = P[l][3];
        pa.l[l].g = P[l][4];  pa.l[l].bb = P[l][5]; pa.l[l].m = P[l][6];
        pa.l[l].v = P[l][7];
        pa.l[l].w1T = w1T[l]; pa.l[l].w2sT = w2sT[l]; pa.l[l].bias2 = bias2[l];
        pa.l[l].DIN = DIN[l]; pa.l[l].DOUT = DOUT[l];
    }
    dim3 pgrid(cdiv_l(64 * 128 + 96 * 64 + 96, B), 3);
    prep_all_kernel<<<pgrid, B, 0, stream>>>(pa, deg, cursor);

    // ---- CSR build + graph bounds ----
    deg_hist_kernel<<<cdiv_l(N_EDGES, B), B, 0, stream>>>(dst, deg, N_EDGES);
    int nblk = cdiv_l(N_NODES, 1024);
    scan1_kernel<<<nblk, 1024, 0, stream>>>(deg, rowptr, partials, N_NODES);
    scan2_kernel<<<1, 128, 0, stream>>>(partials, nblk);
    scan3_kernel<<<cdiv_l(N_NODES + 1, B), B, 0, stream>>>(rowptr, partials, N_NODES, N_EDGES);
    fill_bounds_kernel<<<cdiv_l(N_EDGES, B), B, 0, stream>>>(
        src, dst, rowptr, cursor, eids, batch, gstart, N_EDGES, N_NODES);

    const int ntiles = cdiv_l(N_NODES, 64);

    // ---- layers (ping-pong: yA -> yB -> yA -> h2) ----
    pre_gemm_kernel<<<ntiles, 256, 0, stream>>>(x, w1T[0], yA, N_NODES);
    fused_mid_kernel<<<ntiles, 256, 0, stream>>>(
        yA, rowptr, eids, P[0][1], w2sT[0], bias2[0], w1T[1], yB, N_NODES);
    fused_mid_kernel<<<ntiles, 256, 0, stream>>>(
        yB, rowptr, eids, P[1][1], w2sT[1], bias2[1], w1T[2], yA, N_NODES);
    fused_final_kernel<<<ntiles, 256, 0, stream>>>(
        yA, rowptr, eids, P[2][1], w2sT[2], bias2[2], h2, N_NODES);

    // ---- global mean pool ----
    pool_seg_kernel<<<N_GRAPHS * POOL_SPLIT, 192, 0, stream>>>(h2, gstart, part);
    finalize_kernel<<<cdiv_l(N_GRAPHS * 96, B), B, 0, stream>>>(
        part, gstart, (float*)d_out);
}

// Round 14
// 387.238 us; speedup vs baseline: 1.0484x; 1.0484x over previous
//
#include <hip/hip_runtime.h>

#define N_NODES 100000
#define N_GRAPHS 64
#define N_EDGES 600000
#define BN_EPS 1e-5f

typedef unsigned short bf16_t;

__device__ __forceinline__ unsigned short f2bf(float f) {
    unsigned int u = __float_as_uint(f);
    u += 0x7FFF + ((u >> 16) & 1);
    return (unsigned short)(u >> 16);
}
__device__ __forceinline__ float4 bf2f4(uint2 p) {
    float4 r;
    r.x = __uint_as_float(p.x << 16);
    r.y = __uint_as_float(p.x & 0xFFFF0000u);
    r.z = __uint_as_float(p.y << 16);
    r.w = __uint_as_float(p.y & 0xFFFF0000u);
    return r;
}
__device__ __forceinline__ uint2 pack4(float a, float b, float c, float d) {
    uint2 p;
    p.x = (unsigned)f2bf(a) | ((unsigned)f2bf(b) << 16);
    p.y = (unsigned)f2bf(c) | ((unsigned)f2bf(d) << 16);
    return p;
}
// accumulate 8 bf16 (uint4) into acc[0..7]
__device__ __forceinline__ void bf8_acc(uint4 q, float* acc) {
    acc[0] += __uint_as_float(q.x << 16);
    acc[1] += __uint_as_float(q.x & 0xFFFF0000u);
    acc[2] += __uint_as_float(q.y << 16);
    acc[3] += __uint_as_float(q.y & 0xFFFF0000u);
    acc[4] += __uint_as_float(q.z << 16);
    acc[5] += __uint_as_float(q.z & 0xFFFF0000u);
    acc[6] += __uint_as_float(q.w << 16);
    acc[7] += __uint_as_float(q.w & 0xFFFF0000u);
}

// ===========================================================================
// CSR build: deg histogram -> scan -> cursor fill (+graph bounds merged).
// ===========================================================================
__global__ void deg_hist_kernel(const int* __restrict__ dst,
                                int* __restrict__ deg, int n_edges) {
    int e = blockIdx.x * blockDim.x + threadIdx.x;
    if (e < n_edges) atomicAdd(&deg[dst[e]], 1);
}

__global__ void scan1_kernel(const int* __restrict__ deg, int* __restrict__ excl,
                             int* __restrict__ partials, int n) {
    __shared__ int s[1024];
    int i = blockIdx.x * 1024 + threadIdx.x;
    int v = (i < n) ? deg[i] : 0;
    s[threadIdx.x] = v;
    __syncthreads();
    for (int off = 1; off < 1024; off <<= 1) {
        int t = (threadIdx.x >= (unsigned)off) ? s[threadIdx.x - off] : 0;
        __syncthreads();
        s[threadIdx.x] += t;
        __syncthreads();
    }
    if (i < n) excl[i] = s[threadIdx.x] - v;
    if (threadIdx.x == 1023) partials[blockIdx.x] = s[1023];
}

__global__ void scan2_kernel(int* partials, int nb) {
    __shared__ int s[128];
    int t = threadIdx.x;
    int v = (t < nb) ? partials[t] : 0;
    s[t] = v;
    __syncthreads();
    for (int off = 1; off < 128; off <<= 1) {
        int u = (t >= off) ? s[t - off] : 0;
        __syncthreads();
        s[t] += u;
        __syncthreads();
    }
    if (t < nb) partials[t] = s[t] - v;
}

__global__ void scan3_kernel(int* __restrict__ rowptr, const int* __restrict__ partials,
                             int n, int total) {
    int i = blockIdx.x * blockDim.x + threadIdx.x;
    if (i < n) rowptr[i] += partials[i >> 10];
    else if (i == n) rowptr[n] = total;
}

__global__ void fill_bounds_kernel(const int* __restrict__ src, const int* __restrict__ dst,
                                   const int* __restrict__ rowptr, int* __restrict__ cursor,
                                   int* __restrict__ eids, const int* __restrict__ batch,
                                   int* __restrict__ gstart, int n_edges, int n_nodes) {
    int e = blockIdx.x * blockDim.x + threadIdx.x;
    if (e < n_edges) {
        int t = dst[e];
        int pos = rowptr[t] + atomicAdd(&cursor[t], 1);
        eids[pos] = src[e];
    }
    if (e < n_nodes) {
        if (e == 0) {
            for (int g = 0; g <= batch[0]; ++g) gstart[g] = 0;
        } else {
            int b0 = batch[e - 1], b1 = batch[e];
            for (int g = b0 + 1; g <= b1; ++g) gstart[g] = e;
        }
        if (e == n_nodes - 1) {
            for (int g = batch[e] + 1; g <= N_GRAPHS; ++g) gstart[g] = n_nodes;
        }
    }
}

// ===========================================================================
// Prep, all 3 layers in one launch (blockIdx.y = layer); y==0 blocks also
// zero deg/cursor and d_out (pool atomics accumulate into d_out).
// ===========================================================================
struct LayerPrep {
    const float *w1, *w2, *b2, *g, *bb, *m, *v;
    float *w1T, *w2sT, *bias2;
    int DIN, DOUT;
};
struct PrepAll { LayerPrep l[3]; };

__global__ void prep_all_kernel(PrepAll pa, int* __restrict__ deg,
                                int* __restrict__ cursor, float* __restrict__ out_zero) {
    LayerPrep P = pa.l[blockIdx.y];
    int i = blockIdx.x * blockDim.x + threadIdx.x;
    if (blockIdx.y == 0) {
        int stride = gridDim.x * blockDim.x;
        for (int k = i; k < N_NODES; k += stride) { deg[k] = 0; cursor[k] = 0; }
        for (int k = i; k < N_GRAPHS * 96; k += stride) out_zero[k] = 0.0f;
    }
    if (i < 64 * P.DIN) {
        int j = i / P.DIN, k = i % P.DIN;
        P.w1T[i] = P.w1[k * 64 + j];
    }
    int i2 = i - 64 * P.DIN;
    if (i2 >= 0 && i2 < P.DOUT * 64) {
        int c = i2 / 64, j = i2 % 64;
        float s = P.g[c] * rsqrtf(P.v[c] + BN_EPS);
        P.w2sT[i2] = P.w2[j * P.DOUT + c] * s;
    }
    int i3 = i2 - P.DOUT * 64;
    if (i3 >= 0 && i3 < P.DOUT) {
        float s = P.g[i3] * rsqrtf(P.v[i3] + BN_EPS);
        P.bias2[i3] = (P.b2[i3] - P.m[i3]) * s + P.bb[i3];
    }
}

// ===========================================================================
// pre-GEMM (R10-proven): y = x @ W1_0 (128 -> 64), bf16 out. 64-node tile,
// 256 threads, 4 rows/thread.
// ===========================================================================
__global__ __launch_bounds__(256)
void pre_gemm_kernel(const float* __restrict__ x, const float* __restrict__ w1T,
                     bf16_t* __restrict__ y, int n_nodes) {
    __shared__ float w1s[64 * 128];
    const int tid = threadIdx.x;
    const long base = (long)blockIdx.x * 64;

    const float4* gw1 = (const float4*)w1T;
    for (int i4 = tid; i4 < 16 * 128; i4 += 256) {
        int row = i4 >> 5, k4 = i4 & 31;
        *(float4*)&w1s[row * 128 + ((k4 ^ ((row >> 2) & 7)) << 2)] = gw1[i4];
    }
    __syncthreads();

    const int jg = tid & 15, ng = tid >> 4, xw = jg & 7;
    const float* wp = &w1s[(jg * 4) * 128];
    const float4* xv = (const float4*)x;
    long r[4];
    #pragma unroll
    for (int i = 0; i < 4; ++i) {
        long rr = base + ng * 4 + i;
        r[i] = (rr < n_nodes) ? rr : (n_nodes - 1);  // clamp: x has no padding
    }
    float acc[4][4] = {};
    #pragma unroll 4
    for (int k4 = 0; k4 < 32; ++k4) {
        const int ko = (k4 ^ xw) << 2;
        float4 w0 = *(const float4*)&wp[0 * 128 + ko];
        float4 w1v = *(const float4*)&wp[1 * 128 + ko];
        float4 w2v = *(const float4*)&wp[2 * 128 + ko];
        float4 w3v = *(const float4*)&wp[3 * 128 + ko];
        #pragma unroll
        for (int i = 0; i < 4; ++i) {
            float4 a = xv[r[i] * 32 + k4];
            acc[i][0] = fmaf(a.x, w0.x, fmaf(a.y, w0.y, fmaf(a.z, w0.z, fmaf(a.w, w0.w, acc[i][0]))));
            acc[i][1] = fmaf(a.x, w1v.x, fmaf(a.y, w1v.y, fmaf(a.z, w1v.z, fmaf(a.w, w1v.w, acc[i][1]))));
            acc[i][2] = fmaf(a.x, w2v.x, fmaf(a.y, w2v.y, fmaf(a.z, w2v.z, fmaf(a.w, w2v.w, acc[i][2]))));
            acc[i][3] = fmaf(a.x, w3v.x, fmaf(a.y, w3v.y, fmaf(a.z, w3v.z, fmaf(a.w, w3v.w, acc[i][3]))));
        }
    }
    #pragma unroll
    for (int i = 0; i < 4; ++i) {
        long n = base + ng * 4 + i;
        if (n < n_nodes) {
            *(uint2*)(y + n * 64 + jg * 4) = pack4(acc[i][0], acc[i][1], acc[i][2], acc[i][3]);
        }
    }
}

// ===========================================================================
// Gather (bf16 rows, 8 lanes/row via uint4): t[n] = relu(y[n]+sum_adj+b1).
// One edge-row = one 128 B read by 8 lanes; 8 node chains/wave x unroll 4
// -> 32 outstanding row loads per wave (2x the uint2 version).
// ===========================================================================
__global__ __launch_bounds__(256)
void gather64_kernel(const bf16_t* __restrict__ y, const int* __restrict__ rowptr,
                     const int* __restrict__ eids, const float* __restrict__ b1,
                     float* __restrict__ t, int n_nodes) {
    int node = blockIdx.x * 32 + (threadIdx.x >> 3);
    if (node >= n_nodes) return;
    int f = threadIdx.x & 7;            // 8 feats (one uint4) per lane
    const uint4* yv = (const uint4*)y;  // row = 8 x uint4
    float acc[8] = {};
    bf8_acc(yv[(long)node * 8 + f], acc);
    int b = rowptr[node], e = rowptr[node + 1];
    int i = b;
    for (; i + 3 < e; i += 4) {
        int s0 = eids[i], s1 = eids[i + 1], s2 = eids[i + 2], s3 = eids[i + 3];
        uint4 q0 = yv[(long)s0 * 8 + f];
        uint4 q1 = yv[(long)s1 * 8 + f];
        uint4 q2 = yv[(long)s2 * 8 + f];
        uint4 q3 = yv[(long)s3 * 8 + f];
        bf8_acc(q0, acc); bf8_acc(q1, acc); bf8_acc(q2, acc); bf8_acc(q3, acc);
    }
    for (; i < e; ++i) bf8_acc(yv[(long)eids[i] * 8 + f], acc);

    float4 b0 = ((const float4*)b1)[f * 2];
    float4 b1v = ((const float4*)b1)[f * 2 + 1];
    float4 o0, o1;
    o0.x = fmaxf(acc[0] + b0.x, 0.0f);
    o0.y = fmaxf(acc[1] + b0.y, 0.0f);
    o0.z = fmaxf(acc[2] + b0.z, 0.0f);
    o0.w = fmaxf(acc[3] + b0.w, 0.0f);
    o1.x = fmaxf(acc[4] + b1v.x, 0.0f);
    o1.y = fmaxf(acc[5] + b1v.y, 0.0f);
    o1.z = fmaxf(acc[6] + b1v.z, 0.0f);
    o1.w = fmaxf(acc[7] + b1v.w, 0.0f);
    ((float4*)t)[(long)node * 16 + f * 2] = o0;
    ((float4*)t)[(long)node * 16 + f * 2 + 1] = o1;
}

// ===========================================================================
// Fused mid layer (R10): h = relu(t@W2s + bias2); ynext = h @ W1n (bf16 out).
// ===========================================================================
__global__ __launch_bounds__(256)
void fused_mid_kernel(const float* __restrict__ t, const float* __restrict__ w2sT,
                      const float* __restrict__ bias2, const float* __restrict__ w1nT,
                      bf16_t* __restrict__ ynext, int n_nodes) {
    constexpr int SS = 68;
    __shared__ float sT[64 * SS];
    __shared__ float wbuf[64 * 64];
    const int tid = threadIdx.x;
    const long base = (long)blockIdx.x * 64;

    const float4* gw2 = (const float4*)w2sT;
    for (int i4 = tid; i4 < 16 * 64; i4 += 256) {
        int row = i4 >> 4, k4 = i4 & 15;
        *(float4*)&wbuf[row * 64 + ((k4 ^ ((row >> 2) & 7)) << 2)] = gw2[i4];
    }
    __syncthreads();

    const int jg = tid & 15, ng = tid >> 4, xw = jg & 7;
    const float4* tv = (const float4*)(t + base * 64);

    float h[4][4];
    {
        const float* wp = &wbuf[(jg * 4) * 64];
        float acc[4][4] = {};
        #pragma unroll 4
        for (int k4 = 0; k4 < 16; ++k4) {
            const int ko = (k4 ^ xw) << 2;
            float4 w0 = *(const float4*)&wp[0 * 64 + ko];
            float4 w1v = *(const float4*)&wp[1 * 64 + ko];
            float4 w2v = *(const float4*)&wp[2 * 64 + ko];
            float4 w3v = *(const float4*)&wp[3 * 64 + ko];
            #pragma unroll
            for (int i = 0; i < 4; ++i) {
                float4 a = tv[(ng * 4 + i) * 16 + k4];
                acc[i][0] = fmaf(a.x, w0.x, fmaf(a.y, w0.y, fmaf(a.z, w0.z, fmaf(a.w, w0.w, acc[i][0]))));
                acc[i][1] = fmaf(a.x, w1v.x, fmaf(a.y, w1v.y, fmaf(a.z, w1v.z, fmaf(a.w, w1v.w, acc[i][1]))));
                acc[i][2] = fmaf(a.x, w2v.x, fmaf(a.y, w2v.y, fmaf(a.z, w2v.z, fmaf(a.w, w2v.w, acc[i][2]))));
                acc[i][3] = fmaf(a.x, w3v.x, fmaf(a.y, w3v.y, fmaf(a.z, w3v.z, fmaf(a.w, w3v.w, acc[i][3]))));
            }
        }
        float4 bv = *(const float4*)&bias2[jg * 4];
        #pragma unroll
        for (int i = 0; i < 4; ++i) {
            h[i][0] = fmaxf(acc[i][0] + bv.x, 0.0f);
            h[i][1] = fmaxf(acc[i][1] + bv.y, 0.0f);
            h[i][2] = fmaxf(acc[i][2] + bv.z, 0.0f);
            h[i][3] = fmaxf(acc[i][3] + bv.w, 0.0f);
        }
    }
    __syncthreads();

    #pragma unroll
    for (int i = 0; i < 4; ++i) {
        float4 hv = {h[i][0], h[i][1], h[i][2], h[i][3]};
        *(float4*)&sT[(ng * 4 + i) * SS + jg * 4] = hv;
    }
    const float4* gw1n = (const float4*)w1nT;
    for (int i4 = tid; i4 < 16 * 64; i4 += 256) {
        int row = i4 >> 4, k4 = i4 & 15;
        *(float4*)&wbuf[row * 64 + ((k4 ^ ((row >> 2) & 7)) << 2)] = gw1n[i4];
    }
    __syncthreads();

    {
        const float* ap = &sT[(ng * 4) * SS];
        const float* wp = &wbuf[(jg * 4) * 64];
        float acc[4][4] = {};
        #pragma unroll 4
        for (int k4 = 0; k4 < 16; ++k4) {
            const int ko = (k4 ^ xw) << 2;
            float4 w0 = *(const float4*)&wp[0 * 64 + ko];
            float4 w1v = *(const float4*)&wp[1 * 64 + ko];
            float4 w2v = *(const float4*)&wp[2 * 64 + ko];
            float4 w3v = *(const float4*)&wp[3 * 64 + ko];
            #pragma unroll
            for (int i = 0; i < 4; ++i) {
                float4 a = *(const float4*)&ap[i * SS + k4 * 4];
                acc[i][0] = fmaf(a.x, w0.x, fmaf(a.y, w0.y, fmaf(a.z, w0.z, fmaf(a.w, w0.w, acc[i][0]))));
                acc[i][1] = fmaf(a.x, w1v.x, fmaf(a.y, w1v.y, fmaf(a.z, w1v.z, fmaf(a.w, w1v.w, acc[i][1]))));
                acc[i][2] = fmaf(a.x, w2v.x, fmaf(a.y, w2v.y, fmaf(a.z, w2v.z, fmaf(a.w, w2v.w, acc[i][2]))));
                acc[i][3] = fmaf(a.x, w3v.x, fmaf(a.y, w3v.y, fmaf(a.z, w3v.z, fmaf(a.w, w3v.w, acc[i][3]))));
            }
        }
        #pragma unroll
        for (int i = 0; i < 4; ++i) {
            long n = base + ng * 4 + i;
            if (n < n_nodes) {
                *(uint2*)(ynext + n * 64 + jg * 4) = pack4(acc[i][0], acc[i][1], acc[i][2], acc[i][3]);
            }
        }
    }
}

// ===========================================================================
// Fused final layer (R10): out = relu(t@W2s + bias2), 96-wide fp32.
// ===========================================================================
__global__ __launch_bounds__(256)
void fused_final_kernel(const float* __restrict__ t, const float* __restrict__ w2sT,
                        const float* __restrict__ bias2, float* __restrict__ out,
                        int n_nodes) {
    constexpr int CPT = 6;
    __shared__ float w2s[96 * 64];
    const int tid = threadIdx.x;
    const long base = (long)blockIdx.x * 64;

    const float4* gw2 = (const float4*)w2sT;
    for (int i4 = tid; i4 < 96 * 16; i4 += 256) {
        int row = i4 >> 4, k4 = i4 & 15;
        *(float4*)&w2s[row * 64 + ((k4 ^ ((row / CPT) & 7)) << 2)] = gw2[i4];
    }
    __syncthreads();

    const int cg_ = tid & 15, ng = tid >> 4, xw = cg_ & 7;
    const float4* tv = (const float4*)(t + base * 64);
    const float* wp = &w2s[(cg_ * CPT) * 64];
    float acc[4][CPT] = {};
    #pragma unroll 4
    for (int k4 = 0; k4 < 16; ++k4) {
        const int ko = (k4 ^ xw) << 2;
        float4 wv[CPT];
        #pragma unroll
        for (int c = 0; c < CPT; ++c) wv[c] = *(const float4*)&wp[c * 64 + ko];
        #pragma unroll
        for (int i = 0; i < 4; ++i) {
            float4 h = tv[(ng * 4 + i) * 16 + k4];
            #pragma unroll
            for (int c = 0; c < CPT; ++c)
                acc[i][c] = fmaf(h.x, wv[c].x, fmaf(h.y, wv[c].y, fmaf(h.z, wv[c].z, fmaf(h.w, wv[c].w, acc[i][c]))));
        }
    }
    float bv[CPT];
    #pragma unroll
    for (int c = 0; c < CPT; ++c) bv[c] = bias2[cg_ * CPT + c];
    #pragma unroll
    for (int i = 0; i < 4; ++i) {
        long n = base + ng * 4 + i;
        if (n < n_nodes) {
            float* op = out + n * 96 + cg_ * CPT;
            #pragma unroll
            for (int c = 0; c < CPT; ++c) op[c] = fmaxf(acc[i][c] + bv[c], 0.0f);
        }
    }
}

// ===========================================================================
// Mean-pool: per-(graph,segment) block accumulates, scales by 1/count, and
// atomicAdds into d_out (zeroed by prep_all). Finalize folded in.
// ===========================================================================
#define POOL_SPLIT 16
__global__ __launch_bounds__(192)
void pool_seg_kernel(const float* __restrict__ h, const int* __restrict__ gstart,
                     float* __restrict__ out) {
    int g = blockIdx.x >> 4;
    int s = blockIdx.x & 15;
    int lo = gstart[g], hi = gstart[g + 1];
    int len = hi - lo;
    int seg = (len + POOL_SPLIT - 1) / POOL_SPLIT;
    int a = lo + s * seg;
    int b = a + seg; if (b > hi) b = hi;

    int f4 = threadIdx.x % 24;
    int chain = threadIdx.x / 24;
    const float4* hv = (const float4*)h;
    float4 acc = {0.0f, 0.0f, 0.0f, 0.0f};
    for (int n = a + chain; n < b; n += 8) {
        float4 v = hv[(long)n * 24 + f4];
        acc.x += v.x; acc.y += v.y; acc.z += v.z; acc.w += v.w;
    }
    __shared__ float4 red[8][24];
    red[chain][f4] = acc;
    __syncthreads();
    if (threadIdx.x < 24) {
        float4 t = red[0][threadIdx.x];
        #pragma unroll
        for (int c = 1; c < 8; ++c) {
            float4 r = red[c][threadIdx.x];
            t.x += r.x; t.y += r.y; t.z += r.z; t.w += r.w;
        }
        float inv = 1.0f / fmaxf((float)len, 1.0f);
        float* op = &out[g * 96 + threadIdx.x * 4];
        atomicAdd(op + 0, t.x * inv);
        atomicAdd(op + 1, t.y * inv);
        atomicAdd(op + 2, t.z * inv);
        atomicAdd(op + 3, t.w * inv);
    }
}

// ---------------------------------------------------------------------------
static inline int cdiv_l(long a, int b) { return (int)((a + b - 1) / b); }

extern "C" void kernel_launch(void* const* d_in, const int* in_sizes, int n_in,
                              void* d_out, int out_size, void* d_ws, size_t ws_size,
                              hipStream_t stream) {
    const float* x     = (const float*)d_in[0];
    const int*   ei    = (const int*)d_in[1];
    const int*   src   = ei;
    const int*   dst   = ei + N_EDGES;
    const int*   batch = (const int*)d_in[2];

    const float* P[3][8];
    int p = 3;
    for (int l = 0; l < 3; ++l)
        for (int q = 0; q < 8; ++q)
            P[l][q] = (const float*)d_in[p++];

    const long NP = N_NODES + 128;
    char* wsb   = (char*)d_ws;
    bf16_t* yA  = (bf16_t*)wsb;                       // NP*64 bf16 (ping)
    bf16_t* yB  = yA + NP * 64;                       // NP*64 bf16 (pong)
    float* gB   = (float*)(yB + NP * 64);             // NP*64 fp32 (t)
    float* h2   = gB + NP * 64;                       // NP*96 fp32
    float* q    = h2 + NP * 96;
    float* w1T[3], *w2sT[3], *bias2[3];
    for (int l = 0; l < 3; ++l) {
        w1T[l] = q;   q += 64 * 128;
        w2sT[l] = q;  q += 96 * 64;
        bias2[l] = q; q += 96;
    }
    int* gstart   = (int*)q;
    int* deg      = gstart + 72;
    int* cursor   = deg + N_NODES;
    int* partials = cursor + N_NODES;
    int* rowptr   = partials + 128;
    int* eids     = rowptr + (N_NODES + 1);

    const int B = 256;
    const int DIN[3]  = {128, 64, 64};
    const int DOUT[3] = {64, 64, 96};

    // ---- prep (one launch; also zeroes deg/cursor/d_out) ----
    PrepAll pa;
    for (int l = 0; l < 3; ++l) {
        pa.l[l].w1 = P[l][0]; pa.l[l].w2 = P[l][2]; pa.l[l].b2 = P[l][3];
        pa.l[l].g = P[l][4];  pa.l[l].bb = P[l][5]; pa.l[l].m = P[l][6];
        pa.l[l].v = P[l][7];
        pa.l[l].w1T = w1T[l]; pa.l[l].w2sT = w2sT[l]; pa.l[l].bias2 = bias2[l];
        pa.l[l].DIN = DIN[l]; pa.l[l].DOUT = DOUT[l];
    }
    dim3 pgrid(cdiv_l(64 * 128 + 96 * 64 + 96, B), 3);
    prep_all_kernel<<<pgrid, B, 0, stream>>>(pa, deg, cursor, (float*)d_out);

    // ---- CSR build + graph bounds ----
    deg_hist_kernel<<<cdiv_l(N_EDGES, B), B, 0, stream>>>(dst, deg, N_EDGES);
    int nblk = cdiv_l(N_NODES, 1024);
    scan1_kernel<<<nblk, 1024, 0, stream>>>(deg, rowptr, partials, N_NODES);
    scan2_kernel<<<1, 128, 0, stream>>>(partials, nblk);
    scan3_kernel<<<cdiv_l(N_NODES + 1, B), B, 0, stream>>>(rowptr, partials, N_NODES, N_EDGES);
    fill_bounds_kernel<<<cdiv_l(N_EDGES, B), B, 0, stream>>>(
        src, dst, rowptr, cursor, eids, batch, gstart, N_EDGES, N_NODES);

    const int ntiles = cdiv_l(N_NODES, 64);
    const int ngather = cdiv_l(N_NODES, 32);

    // ---- layer 0 ----
    pre_gemm_kernel<<<ntiles, 256, 0, stream>>>(x, w1T[0], yA, N_NODES);
    gather64_kernel<<<ngather, 256, 0, stream>>>(yA, rowptr, eids, P[0][1], gB, N_NODES);
    fused_mid_kernel<<<ntiles, 256, 0, stream>>>(
        gB, w2sT[0], bias2[0], w1T[1], yB, N_NODES);
    // ---- layer 1 ----
    gather64_kernel<<<ngather, 256, 0, stream>>>(yB, rowptr, eids, P[1][1], gB, N_NODES);
    fused_mid_kernel<<<ntiles, 256, 0, stream>>>(
        gB, w2sT[1], bias2[1], w1T[2], yA, N_NODES);
    // ---- layer 2 ----
    gather64_kernel<<<ngather, 256, 0, stream>>>(yA, rowptr, eids, P[2][1], gB, N_NODES);
    fused_final_kernel<<<ntiles, 256, 0, stream>>>(
        gB, w2sT[2], bias2[2], h2, N_NODES);

    // ---- global mean pool (scaled atomics into pre-zeroed d_out) ----
    pool_seg_kernel<<<N_GRAPHS * POOL_SPLIT, 192, 0, stream>>>(h2, gstart, (float*)d_out);
}

// Round 15
// 377.505 us; speedup vs baseline: 1.0754x; 1.0258x over previous
//
#include <hip/hip_runtime.h>

#define N_NODES 100000
#define N_GRAPHS 64
#define N_EDGES 600000
#define BN_EPS 1e-5f

typedef unsigned short bf16_t;

__device__ __forceinline__ unsigned short f2bf(float f) {
    unsigned int u = __float_as_uint(f);
    u += 0x7FFF + ((u >> 16) & 1);
    return (unsigned short)(u >> 16);
}
__device__ __forceinline__ uint2 pack4(float a, float b, float c, float d) {
    uint2 p;
    p.x = (unsigned)f2bf(a) | ((unsigned)f2bf(b) << 16);
    p.y = (unsigned)f2bf(c) | ((unsigned)f2bf(d) << 16);
    return p;
}
// accumulate 8 bf16 (uint4) into acc[0..7]
__device__ __forceinline__ void bf8_acc(uint4 q, float* acc) {
    acc[0] += __uint_as_float(q.x << 16);
    acc[1] += __uint_as_float(q.x & 0xFFFF0000u);
    acc[2] += __uint_as_float(q.y << 16);
    acc[3] += __uint_as_float(q.y & 0xFFFF0000u);
    acc[4] += __uint_as_float(q.z << 16);
    acc[5] += __uint_as_float(q.z & 0xFFFF0000u);
    acc[6] += __uint_as_float(q.w << 16);
    acc[7] += __uint_as_float(q.w & 0xFFFF0000u);
}

// ===========================================================================
// CSR build
// ===========================================================================
__global__ void deg_hist_kernel(const int* __restrict__ dst,
                                int* __restrict__ deg, int n_edges) {
    int e = blockIdx.x * blockDim.x + threadIdx.x;
    if (e < n_edges) atomicAdd(&deg[dst[e]], 1);
}

// One-kernel exclusive scan: per-block scan + aggregate publish (atomicExch
// into -1-initialized slot) + parallel spin-read of predecessors (atomicAdd,
// device-scope => cross-XCD safe). All 98 blocks co-resident.
__global__ __launch_bounds__(1024)
void scan_fused_kernel(const int* __restrict__ deg, int* __restrict__ rowptr,
                       int* __restrict__ agg, int n, int total) {
    __shared__ int s[1024];
    __shared__ int s2[128];
    __shared__ int offset_sh;
    const int b = blockIdx.x;
    const int i = b * 1024 + threadIdx.x;
    int v = (i < n) ? deg[i] : 0;
    s[threadIdx.x] = v;
    __syncthreads();
    for (int off = 1; off < 1024; off <<= 1) {
        int t = (threadIdx.x >= (unsigned)off) ? s[threadIdx.x - off] : 0;
        __syncthreads();
        s[threadIdx.x] += t;
        __syncthreads();
    }
    // publish this block's total (slot pre-initialized to -1 by prep)
    if (threadIdx.x == 1023) atomicExch(&agg[b], s[1023]);
    // threads 0..b-1 spin-read predecessor aggregates
    if (threadIdx.x < b) {
        int val;
        do { val = atomicAdd(&agg[threadIdx.x], 0); } while (val == -1);
        s2[threadIdx.x] = val;
    }
    __syncthreads();
    if (threadIdx.x == 0) {
        int off = 0;
        for (int k = 0; k < b; ++k) off += s2[k];
        offset_sh = off;
    }
    __syncthreads();
    const int off = offset_sh;
    if (i < n) rowptr[i] = off + s[threadIdx.x] - v;
    else if (i == n) rowptr[n] = total;
}

__global__ void fill_bounds_kernel(const int* __restrict__ src, const int* __restrict__ dst,
                                   const int* __restrict__ rowptr, int* __restrict__ cursor,
                                   int* __restrict__ eids, const int* __restrict__ batch,
                                   int* __restrict__ gstart, int n_edges, int n_nodes) {
    int e = blockIdx.x * blockDim.x + threadIdx.x;
    if (e < n_edges) {
        int t = dst[e];
        int pos = rowptr[t] + atomicAdd(&cursor[t], 1);
        eids[pos] = src[e];
    }
    if (e < n_nodes) {
        if (e == 0) {
            for (int g = 0; g <= batch[0]; ++g) gstart[g] = 0;
        } else {
            int b0 = batch[e - 1], b1 = batch[e];
            for (int g = b0 + 1; g <= b1; ++g) gstart[g] = e;
        }
        if (e == n_nodes - 1) {
            for (int g = batch[e] + 1; g <= N_GRAPHS; ++g) gstart[g] = n_nodes;
        }
    }
}

// ===========================================================================
// Prep (blockIdx.y = layer); y==0 blocks also zero deg/cursor/d_out and
// init scan aggregates to -1.
// ===========================================================================
struct LayerPrep {
    const float *w1, *w2, *b2, *g, *bb, *m, *v;
    float *w1T, *w2sT, *bias2;
    int DIN, DOUT;
};
struct PrepAll { LayerPrep l[3]; };

__global__ void prep_all_kernel(PrepAll pa, int* __restrict__ deg,
                                int* __restrict__ cursor, float* __restrict__ out_zero,
                                int* __restrict__ agg) {
    LayerPrep P = pa.l[blockIdx.y];
    int i = blockIdx.x * blockDim.x + threadIdx.x;
    if (blockIdx.y == 0) {
        int stride = gridDim.x * blockDim.x;
        for (int k = i; k < N_NODES; k += stride) { deg[k] = 0; cursor[k] = 0; }
        for (int k = i; k < N_GRAPHS * 96; k += stride) out_zero[k] = 0.0f;
        if (i < 128) agg[i] = -1;
    }
    if (i < 64 * P.DIN) {
        int j = i / P.DIN, k = i % P.DIN;
        P.w1T[i] = P.w1[k * 64 + j];
    }
    int i2 = i - 64 * P.DIN;
    if (i2 >= 0 && i2 < P.DOUT * 64) {
        int c = i2 / 64, j = i2 % 64;
        float s = P.g[c] * rsqrtf(P.v[c] + BN_EPS);
        P.w2sT[i2] = P.w2[j * P.DOUT + c] * s;
    }
    int i3 = i2 - P.DOUT * 64;
    if (i3 >= 0 && i3 < P.DOUT) {
        float s = P.g[i3] * rsqrtf(P.v[i3] + BN_EPS);
        P.bias2[i3] = (P.b2[i3] - P.m[i3]) * s + P.bb[i3];
    }
}

// ===========================================================================
// pre-GEMM (R10-proven): y = x @ W1_0 (128 -> 64), bf16 out.
// ===========================================================================
__global__ __launch_bounds__(256)
void pre_gemm_kernel(const float* __restrict__ x, const float* __restrict__ w1T,
                     bf16_t* __restrict__ y, int n_nodes) {
    __shared__ float w1s[64 * 128];
    const int tid = threadIdx.x;
    const long base = (long)blockIdx.x * 64;

    const float4* gw1 = (const float4*)w1T;
    for (int i4 = tid; i4 < 16 * 128; i4 += 256) {
        int row = i4 >> 5, k4 = i4 & 31;
        *(float4*)&w1s[row * 128 + ((k4 ^ ((row >> 2) & 7)) << 2)] = gw1[i4];
    }
    __syncthreads();

    const int jg = tid & 15, ng = tid >> 4, xw = jg & 7;
    const float* wp = &w1s[(jg * 4) * 128];
    const float4* xv = (const float4*)x;
    long r[4];
    #pragma unroll
    for (int i = 0; i < 4; ++i) {
        long rr = base + ng * 4 + i;
        r[i] = (rr < n_nodes) ? rr : (n_nodes - 1);  // clamp: x has no padding
    }
    float acc[4][4] = {};
    #pragma unroll 4
    for (int k4 = 0; k4 < 32; ++k4) {
        const int ko = (k4 ^ xw) << 2;
        float4 w0 = *(const float4*)&wp[0 * 128 + ko];
        float4 w1v = *(const float4*)&wp[1 * 128 + ko];
        float4 w2v = *(const float4*)&wp[2 * 128 + ko];
        float4 w3v = *(const float4*)&wp[3 * 128 + ko];
        #pragma unroll
        for (int i = 0; i < 4; ++i) {
            float4 a = xv[r[i] * 32 + k4];
            acc[i][0] = fmaf(a.x, w0.x, fmaf(a.y, w0.y, fmaf(a.z, w0.z, fmaf(a.w, w0.w, acc[i][0]))));
            acc[i][1] = fmaf(a.x, w1v.x, fmaf(a.y, w1v.y, fmaf(a.z, w1v.z, fmaf(a.w, w1v.w, acc[i][1]))));
            acc[i][2] = fmaf(a.x, w2v.x, fmaf(a.y, w2v.y, fmaf(a.z, w2v.z, fmaf(a.w, w2v.w, acc[i][2]))));
            acc[i][3] = fmaf(a.x, w3v.x, fmaf(a.y, w3v.y, fmaf(a.z, w3v.z, fmaf(a.w, w3v.w, acc[i][3]))));
        }
    }
    #pragma unroll
    for (int i = 0; i < 4; ++i) {
        long n = base + ng * 4 + i;
        if (n < n_nodes) {
            *(uint2*)(y + n * 64 + jg * 4) = pack4(acc[i][0], acc[i][1], acc[i][2], acc[i][3]);
        }
    }
}

// ===========================================================================
// Gather (bf16 rows, 8 lanes/row via uint4): t[n] = relu(y[n]+sum_adj+b1).
// ===========================================================================
__global__ __launch_bounds__(256)
void gather64_kernel(const bf16_t* __restrict__ y, const int* __restrict__ rowptr,
                     const int* __restrict__ eids, const float* __restrict__ b1,
                     float* __restrict__ t, int n_nodes) {
    int node = blockIdx.x * 32 + (threadIdx.x >> 3);
    if (node >= n_nodes) return;
    int f = threadIdx.x & 7;
    const uint4* yv = (const uint4*)y;
    float acc[8] = {};
    bf8_acc(yv[(long)node * 8 + f], acc);
    int b = rowptr[node], e = rowptr[node + 1];
    int i = b;
    for (; i + 3 < e; i += 4) {
        int s0 = eids[i], s1 = eids[i + 1], s2 = eids[i + 2], s3 = eids[i + 3];
        uint4 q0 = yv[(long)s0 * 8 + f];
        uint4 q1 = yv[(long)s1 * 8 + f];
        uint4 q2 = yv[(long)s2 * 8 + f];
        uint4 q3 = yv[(long)s3 * 8 + f];
        bf8_acc(q0, acc); bf8_acc(q1, acc); bf8_acc(q2, acc); bf8_acc(q3, acc);
    }
    for (; i < e; ++i) bf8_acc(yv[(long)eids[i] * 8 + f], acc);

    float4 b0 = ((const float4*)b1)[f * 2];
    float4 b1v = ((const float4*)b1)[f * 2 + 1];
    float4 o0, o1;
    o0.x = fmaxf(acc[0] + b0.x, 0.0f);
    o0.y = fmaxf(acc[1] + b0.y, 0.0f);
    o0.z = fmaxf(acc[2] + b0.z, 0.0f);
    o0.w = fmaxf(acc[3] + b0.w, 0.0f);
    o1.x = fmaxf(acc[4] + b1v.x, 0.0f);
    o1.y = fmaxf(acc[5] + b1v.y, 0.0f);
    o1.z = fmaxf(acc[6] + b1v.z, 0.0f);
    o1.w = fmaxf(acc[7] + b1v.w, 0.0f);
    ((float4*)t)[(long)node * 16 + f * 2] = o0;
    ((float4*)t)[(long)node * 16 + f * 2 + 1] = o1;
}

// ===========================================================================
// Fused mid layer: h = relu(t@W2s + bias2); ynext = h @ W1n (bf16 out).
// ===========================================================================
__global__ __launch_bounds__(256)
void fused_mid_kernel(const float* __restrict__ t, const float* __restrict__ w2sT,
                      const float* __restrict__ bias2, const float* __restrict__ w1nT,
                      bf16_t* __restrict__ ynext, int n_nodes) {
    constexpr int SS = 68;
    __shared__ float sT[64 * SS];
    __shared__ float wbuf[64 * 64];
    const int tid = threadIdx.x;
    const long base = (long)blockIdx.x * 64;

    const float4* gw2 = (const float4*)w2sT;
    for (int i4 = tid; i4 < 16 * 64; i4 += 256) {
        int row = i4 >> 4, k4 = i4 & 15;
        *(float4*)&wbuf[row * 64 + ((k4 ^ ((row >> 2) & 7)) << 2)] = gw2[i4];
    }
    __syncthreads();

    const int jg = tid & 15, ng = tid >> 4, xw = jg & 7;
    const float4* tv = (const float4*)(t + base * 64);

    float h[4][4];
    {
        const float* wp = &wbuf[(jg * 4) * 64];
        float acc[4][4] = {};
        #pragma unroll 4
        for (int k4 = 0; k4 < 16; ++k4) {
            const int ko = (k4 ^ xw) << 2;
            float4 w0 = *(const float4*)&wp[0 * 64 + ko];
            float4 w1v = *(const float4*)&wp[1 * 64 + ko];
            float4 w2v = *(const float4*)&wp[2 * 64 + ko];
            float4 w3v = *(const float4*)&wp[3 * 64 + ko];
            #pragma unroll
            for (int i = 0; i < 4; ++i) {
                float4 a = tv[(ng * 4 + i) * 16 + k4];
                acc[i][0] = fmaf(a.x, w0.x, fmaf(a.y, w0.y, fmaf(a.z, w0.z, fmaf(a.w, w0.w, acc[i][0]))));
                acc[i][1] = fmaf(a.x, w1v.x, fmaf(a.y, w1v.y, fmaf(a.z, w1v.z, fmaf(a.w, w1v.w, acc[i][1]))));
                acc[i][2] = fmaf(a.x, w2v.x, fmaf(a.y, w2v.y, fmaf(a.z, w2v.z, fmaf(a.w, w2v.w, acc[i][2]))));
                acc[i][3] = fmaf(a.x, w3v.x, fmaf(a.y, w3v.y, fmaf(a.z, w3v.z, fmaf(a.w, w3v.w, acc[i][3]))));
            }
        }
        float4 bv = *(const float4*)&bias2[jg * 4];
        #pragma unroll
        for (int i = 0; i < 4; ++i) {
            h[i][0] = fmaxf(acc[i][0] + bv.x, 0.0f);
            h[i][1] = fmaxf(acc[i][1] + bv.y, 0.0f);
            h[i][2] = fmaxf(acc[i][2] + bv.z, 0.0f);
            h[i][3] = fmaxf(acc[i][3] + bv.w, 0.0f);
        }
    }
    __syncthreads();

    #pragma unroll
    for (int i = 0; i < 4; ++i) {
        float4 hv = {h[i][0], h[i][1], h[i][2], h[i][3]};
        *(float4*)&sT[(ng * 4 + i) * SS + jg * 4] = hv;
    }
    const float4* gw1n = (const float4*)w1nT;
    for (int i4 = tid; i4 < 16 * 64; i4 += 256) {
        int row = i4 >> 4, k4 = i4 & 15;
        *(float4*)&wbuf[row * 64 + ((k4 ^ ((row >> 2) & 7)) << 2)] = gw1n[i4];
    }
    __syncthreads();

    {
        const float* ap = &sT[(ng * 4) * SS];
        const float* wp = &wbuf[(jg * 4) * 64];
        float acc[4][4] = {};
        #pragma unroll 4
        for (int k4 = 0; k4 < 16; ++k4) {
            const int ko = (k4 ^ xw) << 2;
            float4 w0 = *(const float4*)&wp[0 * 64 + ko];
            float4 w1v = *(const float4*)&wp[1 * 64 + ko];
            float4 w2v = *(const float4*)&wp[2 * 64 + ko];
            float4 w3v = *(const float4*)&wp[3 * 64 + ko];
            #pragma unroll
            for (int i = 0; i < 4; ++i) {
                float4 a = *(const float4*)&ap[i * SS + k4 * 4];
                acc[i][0] = fmaf(a.x, w0.x, fmaf(a.y, w0.y, fmaf(a.z, w0.z, fmaf(a.w, w0.w, acc[i][0]))));
                acc[i][1] = fmaf(a.x, w1v.x, fmaf(a.y, w1v.y, fmaf(a.z, w1v.z, fmaf(a.w, w1v.w, acc[i][1]))));
                acc[i][2] = fmaf(a.x, w2v.x, fmaf(a.y, w2v.y, fmaf(a.z, w2v.z, fmaf(a.w, w2v.w, acc[i][2]))));
                acc[i][3] = fmaf(a.x, w3v.x, fmaf(a.y, w3v.y, fmaf(a.z, w3v.z, fmaf(a.w, w3v.w, acc[i][3]))));
            }
        }
        #pragma unroll
        for (int i = 0; i < 4; ++i) {
            long n = base + ng * 4 + i;
            if (n < n_nodes) {
                *(uint2*)(ynext + n * 64 + jg * 4) = pack4(acc[i][0], acc[i][1], acc[i][2], acc[i][3]);
            }
        }
    }
}

// ===========================================================================
// Fused final layer + mean-pool: out96 = relu(t@W2s + bias2); then the 24 KB
// weight LDS buffer is REUSED as hbuf[64][96] (exactly 6144 floats) and
// threads 0..95 walk the sorted-batch rows, flushing scaled atomicAdds into
// pre-zeroed d_out. No h2 buffer, no pool dispatch.
// ===========================================================================
__global__ __launch_bounds__(256)
void fused_final_kernel(const float* __restrict__ t, const float* __restrict__ w2sT,
                        const float* __restrict__ bias2, const int* __restrict__ batch,
                        const int* __restrict__ gstart, float* __restrict__ out,
                        int n_nodes) {
    constexpr int CPT = 6;
    __shared__ float w2s[96 * 64];  // later reused as hbuf[64][96]
    const int tid = threadIdx.x;
    const long base = (long)blockIdx.x * 64;

    const float4* gw2 = (const float4*)w2sT;
    for (int i4 = tid; i4 < 96 * 16; i4 += 256) {
        int row = i4 >> 4, k4 = i4 & 15;
        *(float4*)&w2s[row * 64 + ((k4 ^ ((row / CPT) & 7)) << 2)] = gw2[i4];
    }
    __syncthreads();

    const int cg_ = tid & 15, ng = tid >> 4, xw = cg_ & 7;
    const float4* tv = (const float4*)(t + base * 64);
    const float* wp = &w2s[(cg_ * CPT) * 64];
    float acc[4][CPT] = {};
    #pragma unroll 4
    for (int k4 = 0; k4 < 16; ++k4) {
        const int ko = (k4 ^ xw) << 2;
        float4 wv[CPT];
        #pragma unroll
        for (int c = 0; c < CPT; ++c) wv[c] = *(const float4*)&wp[c * 64 + ko];
        #pragma unroll
        for (int i = 0; i < 4; ++i) {
            float4 h = tv[(ng * 4 + i) * 16 + k4];
            #pragma unroll
            for (int c = 0; c < CPT; ++c)
                acc[i][c] = fmaf(h.x, wv[c].x, fmaf(h.y, wv[c].y, fmaf(h.z, wv[c].z, fmaf(h.w, wv[c].w, acc[i][c]))));
        }
    }
    float bv[CPT];
    #pragma unroll
    for (int c = 0; c < CPT; ++c) bv[c] = bias2[cg_ * CPT + c];
    __syncthreads();  // all w2s weight reads done; buffer becomes hbuf
    #pragma unroll
    for (int i = 0; i < 4; ++i) {
        long n = base + ng * 4 + i;
        float* hp = &w2s[(ng * 4 + i) * 96 + cg_ * CPT];
        if (n < n_nodes) {
            #pragma unroll
            for (int c = 0; c < CPT; ++c) hp[c] = fmaxf(acc[i][c] + bv[c], 0.0f);
        } else {
            #pragma unroll
            for (int c = 0; c < CPT; ++c) hp[c] = 0.0f;
        }
    }
    __syncthreads();

    // per-graph column sums over this block's 64 sorted rows
    if (tid < 96) {
        int limit = (int)((n_nodes - base < 64) ? (n_nodes - base) : 64);
        int gcur = batch[base];
        float s = 0.0f;
        for (int r = 0; r < limit; ++r) {
            int g = batch[base + r];
            if (g != gcur) {
                float inv = 1.0f / fmaxf((float)(gstart[gcur + 1] - gstart[gcur]), 1.0f);
                atomicAdd(&out[gcur * 96 + tid], s * inv);
                s = 0.0f;
                gcur = g;
            }
            s += w2s[r * 96 + tid];
        }
        float inv = 1.0f / fmaxf((float)(gstart[gcur + 1] - gstart[gcur]), 1.0f);
        atomicAdd(&out[gcur * 96 + tid], s * inv);
    }
}

// ---------------------------------------------------------------------------
static inline int cdiv_l(long a, int b) { return (int)((a + b - 1) / b); }

extern "C" void kernel_launch(void* const* d_in, const int* in_sizes, int n_in,
                              void* d_out, int out_size, void* d_ws, size_t ws_size,
                              hipStream_t stream) {
    const float* x     = (const float*)d_in[0];
    const int*   ei    = (const int*)d_in[1];
    const int*   src   = ei;
    const int*   dst   = ei + N_EDGES;
    const int*   batch = (const int*)d_in[2];

    const float* P[3][8];
    int p = 3;
    for (int l = 0; l < 3; ++l)
        for (int q = 0; q < 8; ++q)
            P[l][q] = (const float*)d_in[p++];

    const long NP = N_NODES + 128;
    char* wsb   = (char*)d_ws;
    bf16_t* yA  = (bf16_t*)wsb;                       // NP*64 bf16 (ping)
    bf16_t* yB  = yA + NP * 64;                       // NP*64 bf16 (pong)
    float* gB   = (float*)(yB + NP * 64);             // NP*64 fp32 (t)
    float* q    = gB + NP * 64;
    float* w1T[3], *w2sT[3], *bias2[3];
    for (int l = 0; l < 3; ++l) {
        w1T[l] = q;   q += 64 * 128;
        w2sT[l] = q;  q += 96 * 64;
        bias2[l] = q; q += 96;
    }
    int* gstart   = (int*)q;
    int* deg      = gstart + 72;
    int* cursor   = deg + N_NODES;
    int* partials = cursor + N_NODES;   // scan aggregates (init -1)
    int* rowptr   = partials + 128;
    int* eids     = rowptr + (N_NODES + 1);

    const int B = 256;
    const int DIN[3]  = {128, 64, 64};
    const int DOUT[3] = {64, 64, 96};

    // ---- prep (zero deg/cursor/d_out, init scan slots, fold weights) ----
    PrepAll pa;
    for (int l = 0; l < 3; ++l) {
        pa.l[l].w1 = P[l][0]; pa.l[l].w2 = P[l][2]; pa.l[l].b2 = P[l][3];
        pa.l[l].g = P[l][4];  pa.l[l].bb = P[l][5]; pa.l[l].m = P[l][6];
        pa.l[l].v = P[l][7];
        pa.l[l].w1T = w1T[l]; pa.l[l].w2sT = w2sT[l]; pa.l[l].bias2 = bias2[l];
        pa.l[l].DIN = DIN[l]; pa.l[l].DOUT = DOUT[l];
    }
    dim3 pgrid(cdiv_l(64 * 128 + 96 * 64 + 96, B), 3);
    prep_all_kernel<<<pgrid, B, 0, stream>>>(pa, deg, cursor, (float*)d_out, partials);

    // ---- CSR build + graph bounds ----
    deg_hist_kernel<<<cdiv_l(N_EDGES, B), B, 0, stream>>>(dst, deg, N_EDGES);
    int nblk = cdiv_l(N_NODES + 1, 1024);  // 98 blocks, all co-resident
    scan_fused_kernel<<<nblk, 1024, 0, stream>>>(deg, rowptr, partials, N_NODES, N_EDGES);
    fill_bounds_kernel<<<cdiv_l(N_EDGES, B), B, 0, stream>>>(
        src, dst, rowptr, cursor, eids, batch, gstart, N_EDGES, N_NODES);

    const int ntiles = cdiv_l(N_NODES, 64);
    const int ngather = cdiv_l(N_NODES, 32);

    // ---- layer 0 ----
    pre_gemm_kernel<<<ntiles, 256, 0, stream>>>(x, w1T[0], yA, N_NODES);
    gather64_kernel<<<ngather, 256, 0, stream>>>(yA, rowptr, eids, P[0][1], gB, N_NODES);
    fused_mid_kernel<<<ntiles, 256, 0, stream>>>(
        gB, w2sT[0], bias2[0], w1T[1], yB, N_NODES);
    // ---- layer 1 ----
    gather64_kernel<<<ngather, 256, 0, stream>>>(yB, rowptr, eids, P[1][1], gB, N_NODES);
    fused_mid_kernel<<<ntiles, 256, 0, stream>>>(
        gB, w2sT[1], bias2[1], w1T[2], yA, N_NODES);
    // ---- layer 2 (+ pool fused) ----
    gather64_kernel<<<ngather, 256, 0, stream>>>(yA, rowptr, eids, P[2][1], gB, N_NODES);
    fused_final_kernel<<<ntiles, 256, 0, stream>>>(
        gB, w2sT[2], bias2[2], batch, gstart, (float*)d_out, N_NODES);
}